// Round 9
// baseline (427.982 us; speedup 1.0000x reference)
//
#include <hip/hip_runtime.h>
#include <hip/hip_bf16.h>

// QHNet block-linear layer. R8 = DIAGNOSTIC: exact R2 champion (224us)
// with grid doubled (b0 = bid%6250): two blocks write identical output
// bytes -> deterministic, passes validation, and the main dispatch becomes
// ~450us so it finally appears in rocprof top-5 (harness 2.5GB fills at
// ~380us have hidden our kernel's counters all session).
// Counters to read: FETCH_SIZE (write-amplification discriminator),
// WRITE_SIZE, hbm_gbps, MfmaUtil, VALUBusy, Occupancy, LDS_BANK_CONFLICT.
// All at exactly 2x the real single-pass workload.

typedef short bf16x8 __attribute__((ext_vector_type(8)));
typedef float f32x4 __attribute__((ext_vector_type(4)));

static __device__ __forceinline__ unsigned short f2bf(float f) {
    __hip_bfloat16 h = __float2bfloat16(f);
    union { __hip_bfloat16 h; unsigned short u; } cvt; cvt.h = h;
    return cvt.u;
}

// ---- weight prep: transpose to W[n][k] bf16 with scales folded -------------
__global__ void prep_w(const float* __restrict__ w,
                       unsigned short* __restrict__ w0t,
                       unsigned short* __restrict__ w1t) {
    int idx = blockIdx.x * 256 + threadIdx.x;   // 240*256 == 61440 exactly
    const float S000 = 1.0f / 128.0f;
    const float S011 = 1.0f / (128.0f * 1.7320508075688772f);
    const float S1X  = 1.0f / (64.0f * 1.7320508075688772f);
    const float S111 = 1.0f / (64.0f * 2.449489742783178f);
    if (idx < 320 * 128) {
        int n = idx >> 7, k = idx & 127;
        float v;
        if (n < 256) v = w[k * 256 + n] * S000;                 // w000[k][uv]
        else         v = w[32768 + k * 64 + (n - 256)] * S011;  // w011[k][uv]
        w0t[idx] = f2bf(v);
    } else {
        int i2 = idx - 320 * 128;
        int n = i2 >> 6, k = i2 & 63;
        float v;
        if (n < 128)      v = w[40960 + k * 128 + n] * S1X;           // w101
        else if (n < 256) v = w[49152 + k * 128 + (n - 128)] * S1X;   // w110
        else              v = w[57344 + k * 64  + (n - 256)] * S111;  // w111
        w1t[i2] = f2bf(v);
    }
}

// ---- main fused kernel (R2 structure, verbatim) ----------------------------
__global__ __launch_bounds__(256) void qhnet_main(
    const float* __restrict__ x_in,
    const unsigned short* __restrict__ w0t,
    const unsigned short* __restrict__ w1t,
    float* __restrict__ out,
    int ntiles)
{
    __shared__ __attribute__((aligned(16))) float smemf[8 * 1600];
    unsigned short* x0L = reinterpret_cast<unsigned short*>(smemf); // [16][128]
    unsigned short* x1L = x0L + 16 * 128;                           // [3][16][64]

    const int tid = threadIdx.x;
    int bid = blockIdx.x;
    if (bid >= ntiles) bid -= ntiles;       // duplicate pass (diagnostic 2x)
    const int b0 = bid * 16;

    // --- stage x tile -> LDS as bf16 (coalesced float4 reads) ---
    const float4* xrow = reinterpret_cast<const float4*>(x_in + (size_t)b0 * 320);
    for (int p = tid; p < 16 * 80; p += 256) {
        int row = p / 80;
        int c4 = p - row * 80;
        float4 v = xrow[p];
        int sw = (row & 7) << 3;
        int col = c4 * 4;
        if (col < 128) {
            int k = col ^ sw;
            ushort4 u;
            u.x = f2bf(v.x); u.y = f2bf(v.y); u.z = f2bf(v.z); u.w = f2bf(v.w);
            *reinterpret_cast<ushort4*>(&x0L[row * 128 + k]) = u;
        } else {
            float vv[4] = {v.x, v.y, v.z, v.w};
            #pragma unroll
            for (int e = 0; e < 4; ++e) {
                int f = col - 128 + e;
                int wi = f / 3, cm = f - wi * 3;
                x1L[cm * 1024 + row * 64 + (wi ^ sw)] = f2bf(vv[e]);
            }
        }
    }
    __syncthreads();

    const int lane = tid & 63;
    const int wv = tid >> 6;
    const int cn = lane & 15;
    const int grp = lane >> 4;
    const int swf = (cn & 7) << 3;

    bf16x8 a0[4], a1[3][2];
    #pragma unroll
    for (int ks = 0; ks < 4; ++ks)
        a0[ks] = *reinterpret_cast<const bf16x8*>(
            &x0L[cn * 128 + ((ks * 32 + grp * 8) ^ swf)]);
    #pragma unroll
    for (int c = 0; c < 3; ++c)
        #pragma unroll
        for (int ks = 0; ks < 2; ++ks)
            a1[c][ks] = *reinterpret_cast<const bf16x8*>(
                &x1L[c * 1024 + cn * 64 + ((ks * 32 + grp * 8) ^ swf)]);

    f32x4 acc0[5] = {};
    f32x4 acc1[3][5] = {};

    const int c0base[5] = {wv * 64, wv * 64 + 16, wv * 64 + 32, wv * 64 + 48,
                           256 + wv * 16};
    const int c1base[5] = {wv * 32, wv * 32 + 16, 128 + wv * 32,
                           128 + wv * 32 + 16, 256 + wv * 16};

    #pragma unroll
    for (int t = 0; t < 5; ++t) {
        const unsigned short* wp = w0t + (c0base[t] + cn) * 128 + grp * 8;
        #pragma unroll
        for (int ks = 0; ks < 4; ++ks) {
            bf16x8 b = *reinterpret_cast<const bf16x8*>(wp + ks * 32);
            acc0[t] = __builtin_amdgcn_mfma_f32_16x16x32_bf16(a0[ks], b, acc0[t], 0, 0, 0);
        }
    }
    #pragma unroll
    for (int t = 0; t < 5; ++t) {
        const unsigned short* wp = w1t + (c1base[t] + cn) * 64 + grp * 8;
        #pragma unroll
        for (int ks = 0; ks < 2; ++ks) {
            bf16x8 b = *reinterpret_cast<const bf16x8*>(wp + ks * 32);
            #pragma unroll
            for (int c = 0; c < 3; ++c)
                acc1[c][t] = __builtin_amdgcn_mfma_f32_16x16x32_bf16(a1[c][ks], b, acc1[c][t], 0, 0, 0);
        }
    }

    // --- epilogue: scatter accs -> LDS (8 rows/phase), then coalesced copy ---
    // C/D frag: row (=batch in tile) = grp*4 + r, col (=n) = cn
    const int rbase = (grp & 1) * 4;

    #pragma unroll
    for (int h = 0; h < 2; ++h) {
        __syncthreads();
        if ((grp >> 1) == h) {
            #pragma unroll
            for (int t = 0; t < 4; ++t) {               // blk00
                int u = wv * 4 + t;
                #pragma unroll
                for (int r = 0; r < 4; ++r)
                    smemf[(rbase + r) * 1600 + u * 40 + cn] = acc0[t][r];
            }
            #pragma unroll
            for (int t = 0; t < 2; ++t) {               // blk01 + blk10
                int n01 = wv * 32 + t * 16 + cn;
                int u01 = n01 >> 3, v01 = n01 & 7;
                int u10 = n01 >> 4, v10 = n01 & 15;
                #pragma unroll
                for (int r = 0; r < 4; ++r) {
                    float* o01 = &smemf[(rbase + r) * 1600 + u01 * 40 + 16 + 3 * v01];
                    o01[0] = acc1[0][t][r];
                    o01[1] = acc1[1][t][r];
                    o01[2] = acc1[2][t][r];
                    #pragma unroll
                    for (int c = 0; c < 3; ++c)
                        smemf[(rbase + r) * 1600 + (16 + 3 * u10 + c) * 40 + v10] = acc1[c][t + 2][r];
                }
            }
            {                                           // blk11
                int uv = wv * 16 + cn, u = uv >> 3, v = uv & 7;
                #pragma unroll
                for (int r = 0; r < 4; ++r) {
                    float d  = acc0[4][r];
                    float t0 = acc1[0][4][r], t1 = acc1[1][4][r], t2 = acc1[2][4][r];
                    float* o = &smemf[(rbase + r) * 1600 + (16 + 3 * u) * 40 + 16 + 3 * v];
                    o[0]  = d;    o[1]  = t2;   o[2]  = -t1;
                    o[40] = -t2;  o[41] = d;    o[42] = t0;
                    o[80] = t1;   o[81] = -t0;  o[82] = d;
                }
            }
        }
        __syncthreads();
        float4* dst = reinterpret_cast<float4*>(out + (size_t)(b0 + h * 8) * 1600);
        const float4* srcv = reinterpret_cast<const float4*>(smemf);
        for (int p = tid; p < 3200; p += 256)
            dst[p] = srcv[p];
    }
}

extern "C" void kernel_launch(void* const* d_in, const int* in_sizes, int n_in,
                              void* d_out, int out_size, void* d_ws, size_t ws_size,
                              hipStream_t stream) {
    const float* x_in = (const float*)d_in[0];
    const float* weights = (const float*)d_in[1];
    float* out = (float*)d_out;
    unsigned short* w0t = (unsigned short*)d_ws;            // 320*128 bf16
    unsigned short* w1t = w0t + 320 * 128;                  // 320*64  bf16
    int B = in_sizes[0] / 320;                              // 100000
    int ntiles = B / 16;                                    // 6250

    prep_w<<<240, 256, 0, stream>>>(weights, w0t, w1t);
    // DIAGNOSTIC: 2x grid, second half re-writes identical bytes.
    qhnet_main<<<2 * ntiles, 256, 0, stream>>>(x_in, w0t, w1t, out, ntiles);
}

// Round 10
// 165.060 us; speedup vs baseline: 2.5929x; 2.5929x over previous
//
#include <hip/hip_runtime.h>
#include <hip/hip_bf16.h>

// QHNet block-linear layer. R10: persistent pipelined blocks.
// R9 counters (2x diagnostic): FETCH 136MB (no write-allocate amp), WRITE
// exactly 2x640MB, BW 3.2TB/s (40%), MfmaUtil 3.8%, VALUBusy 13%, Occ 34%
// -> latency/serialization-bound, not traffic-bound. Fix: each block loops
// over ~12 tiles (grid=512=2/CU), double-buffered x staging, LGKM-only
// barriers (stores NEVER drained mid-kernel -> fire-and-forget across
// tiles), stage-load(t+1) issued before MFMA(t) to hide HBM latency.
// Epilogue = R2's proven scalar-scatter 2-phase + nt coalesced copy-out.

typedef short bf16x8 __attribute__((ext_vector_type(8)));
typedef float f32x4 __attribute__((ext_vector_type(4)));

#define LGKM_BARRIER()                                         \
    do {                                                       \
        asm volatile("s_waitcnt lgkmcnt(0)" ::: "memory");     \
        __builtin_amdgcn_sched_barrier(0);                     \
        __builtin_amdgcn_s_barrier();                          \
        __builtin_amdgcn_sched_barrier(0);                     \
    } while (0)

static __device__ __forceinline__ unsigned short f2bf(float f) {
    __hip_bfloat16 h = __float2bfloat16(f);
    union { __hip_bfloat16 h; unsigned short u; } cvt; cvt.h = h;
    return cvt.u;
}

// ---- weight prep: transpose to W[n][k] bf16 with scales folded -------------
__global__ void prep_w(const float* __restrict__ w,
                       unsigned short* __restrict__ w0t,
                       unsigned short* __restrict__ w1t) {
    int idx = blockIdx.x * 256 + threadIdx.x;   // 240*256 == 61440 exactly
    const float S000 = 1.0f / 128.0f;
    const float S011 = 1.0f / (128.0f * 1.7320508075688772f);
    const float S1X  = 1.0f / (64.0f * 1.7320508075688772f);
    const float S111 = 1.0f / (64.0f * 2.449489742783178f);
    if (idx < 320 * 128) {
        int n = idx >> 7, k = idx & 127;
        float v;
        if (n < 256) v = w[k * 256 + n] * S000;                 // w000[k][uv]
        else         v = w[32768 + k * 64 + (n - 256)] * S011;  // w011[k][uv]
        w0t[idx] = f2bf(v);
    } else {
        int i2 = idx - 320 * 128;
        int n = i2 >> 6, k = i2 & 63;
        float v;
        if (n < 128)      v = w[40960 + k * 128 + n] * S1X;           // w101
        else if (n < 256) v = w[49152 + k * 128 + (n - 128)] * S1X;   // w110
        else              v = w[57344 + k * 64  + (n - 256)] * S111;  // w111
        w1t[i2] = f2bf(v);
    }
}

#define GRID 512

// ---- main fused persistent kernel ------------------------------------------
__global__ __launch_bounds__(256) void qhnet_main(
    const float* __restrict__ x_in,
    const unsigned short* __restrict__ w0t,
    const unsigned short* __restrict__ w1t,
    float* __restrict__ out,
    int ntiles)
{
    __shared__ __attribute__((aligned(16))) float smemf[8 * 1600];   // out tile
    __shared__ __attribute__((aligned(16))) unsigned short xbuf[2][16 * 320];

    const int tid = threadIdx.x;
    const int lane = tid & 63;
    const int wv = tid >> 6;
    const int cn = lane & 15;
    const int grp = lane >> 4;
    const int swf = (cn & 7) << 3;
    const int rbase = (grp & 1) * 4;

    const int c0base[5] = {wv * 64, wv * 64 + 16, wv * 64 + 32, wv * 64 + 48,
                           256 + wv * 16};
    const int c1base[5] = {wv * 32, wv * 32 + 16, 128 + wv * 32,
                           128 + wv * 32 + 16, 256 + wv * 16};

    // precompute staging decode for the 5 per-thread quads
    // p = tid + k*256; row=p/80; col=(p-row*80)*4
    int s_row[5], s_col[5];
    #pragma unroll
    for (int k = 0; k < 5; ++k) {
        int p = tid + (k << 8);
        s_row[k] = p / 80;
        s_col[k] = (p - s_row[k] * 80) * 4;
    }

    // ---- prologue: stage first tile into buf 0 ----
    int t = blockIdx.x;
    {
        const f32x4* xrow = reinterpret_cast<const f32x4*>(x_in + (size_t)t * 16 * 320);
        #pragma unroll
        for (int k = 0; k < 5; ++k) {
            f32x4 v = __builtin_nontemporal_load(&xrow[tid + (k << 8)]);
            int row = s_row[k], col = s_col[k], sw = (row & 7) << 3;
            if (col < 128) {
                ushort4 u;
                u.x = f2bf(v[0]); u.y = f2bf(v[1]); u.z = f2bf(v[2]); u.w = f2bf(v[3]);
                *reinterpret_cast<ushort4*>(&xbuf[0][row * 128 + (col ^ sw)]) = u;
            } else {
                #pragma unroll
                for (int e = 0; e < 4; ++e) {
                    int f = col - 128 + e;
                    int wi = f / 3, cm = f - wi * 3;
                    xbuf[0][2048 + cm * 1024 + row * 64 + (wi ^ sw)] = f2bf(v[e]);
                }
            }
        }
    }
    LGKM_BARRIER();

    int cur = 0;
    for (; t < ntiles; t += GRID) {
        const int b0 = t * 16;

        // --- fragment reads from xbuf[cur] ---
        bf16x8 a0[4], a1[3][2];
        {
            const unsigned short* x0L = &xbuf[cur][0];
            const unsigned short* x1L = &xbuf[cur][2048];
            #pragma unroll
            for (int ks = 0; ks < 4; ++ks)
                a0[ks] = *reinterpret_cast<const bf16x8*>(
                    &x0L[cn * 128 + ((ks * 32 + grp * 8) ^ swf)]);
            #pragma unroll
            for (int c = 0; c < 3; ++c)
                #pragma unroll
                for (int ks = 0; ks < 2; ++ks)
                    a1[c][ks] = *reinterpret_cast<const bf16x8*>(
                        &x1L[c * 1024 + cn * 64 + ((ks * 32 + grp * 8) ^ swf)]);
        }

        // --- issue next tile's loads early (hide HBM latency under MFMA) ---
        const bool more = (t + GRID) < ntiles;
        f32x4 v[5];
        if (more) {
            const f32x4* xrow = reinterpret_cast<const f32x4*>(
                x_in + (size_t)(t + GRID) * 16 * 320);
            #pragma unroll
            for (int k = 0; k < 5; ++k)
                v[k] = __builtin_nontemporal_load(&xrow[tid + (k << 8)]);
        }

        // --- MFMA ---
        f32x4 acc0[5] = {};
        f32x4 acc1[3][5] = {};
        #pragma unroll
        for (int tt = 0; tt < 5; ++tt) {
            const unsigned short* wp = w0t + (c0base[tt] + cn) * 128 + grp * 8;
            #pragma unroll
            for (int ks = 0; ks < 4; ++ks) {
                bf16x8 b = *reinterpret_cast<const bf16x8*>(wp + ks * 32);
                acc0[tt] = __builtin_amdgcn_mfma_f32_16x16x32_bf16(a0[ks], b, acc0[tt], 0, 0, 0);
            }
        }
        #pragma unroll
        for (int tt = 0; tt < 5; ++tt) {
            const unsigned short* wp = w1t + (c1base[tt] + cn) * 64 + grp * 8;
            #pragma unroll
            for (int ks = 0; ks < 2; ++ks) {
                bf16x8 b = *reinterpret_cast<const bf16x8*>(wp + ks * 32);
                #pragma unroll
                for (int c = 0; c < 3; ++c)
                    acc1[c][tt] = __builtin_amdgcn_mfma_f32_16x16x32_bf16(a1[c][ks], b, acc1[c][tt], 0, 0, 0);
            }
        }

        // --- write next tile's staging (loads have had MFMA-time to land) ---
        if (more) {
            const int nb = cur ^ 1;
            #pragma unroll
            for (int k = 0; k < 5; ++k) {
                int row = s_row[k], col = s_col[k], sw = (row & 7) << 3;
                if (col < 128) {
                    ushort4 u;
                    u.x = f2bf(v[k][0]); u.y = f2bf(v[k][1]);
                    u.z = f2bf(v[k][2]); u.w = f2bf(v[k][3]);
                    *reinterpret_cast<ushort4*>(&xbuf[nb][row * 128 + (col ^ sw)]) = u;
                } else {
                    #pragma unroll
                    for (int e = 0; e < 4; ++e) {
                        int f = col - 128 + e;
                        int wi = f / 3, cm = f - wi * 3;
                        xbuf[nb][2048 + cm * 1024 + row * 64 + (wi ^ sw)] = f2bf(v[k][e]);
                    }
                }
            }
        }
        LGKM_BARRIER();   // staging(t+1) visible; frag-reads(t) done everywhere;
                          // prev iteration's copy-out LDS reads done

        // --- epilogue: 2 phases x 8 rows (R2 scalar scatter) ---
        #pragma unroll
        for (int h = 0; h < 2; ++h) {
            if (h) LGKM_BARRIER();      // copy h0 LDS reads done
            if ((grp >> 1) == h) {
                #pragma unroll
                for (int tt = 0; tt < 4; ++tt) {            // blk00
                    int u = wv * 4 + tt;
                    #pragma unroll
                    for (int r = 0; r < 4; ++r)
                        smemf[(rbase + r) * 1600 + u * 40 + cn] = acc0[tt][r];
                }
                #pragma unroll
                for (int tt = 0; tt < 2; ++tt) {            // blk01 + blk10
                    int n01 = wv * 32 + tt * 16 + cn;
                    int u01 = n01 >> 3, v01 = n01 & 7;
                    int u10 = n01 >> 4, v10 = n01 & 15;
                    #pragma unroll
                    for (int r = 0; r < 4; ++r) {
                        float* o01 = &smemf[(rbase + r) * 1600 + u01 * 40 + 16 + 3 * v01];
                        o01[0] = acc1[0][tt][r];
                        o01[1] = acc1[1][tt][r];
                        o01[2] = acc1[2][tt][r];
                        #pragma unroll
                        for (int c = 0; c < 3; ++c)
                            smemf[(rbase + r) * 1600 + (16 + 3 * u10 + c) * 40 + v10] = acc1[c][tt + 2][r];
                    }
                }
                {                                           // blk11
                    int uv = wv * 16 + cn, u = uv >> 3, vv2 = uv & 7;
                    #pragma unroll
                    for (int r = 0; r < 4; ++r) {
                        float d  = acc0[4][r];
                        float t0 = acc1[0][4][r], t1 = acc1[1][4][r], t2 = acc1[2][4][r];
                        float* o = &smemf[(rbase + r) * 1600 + (16 + 3 * u) * 40 + 16 + 3 * vv2];
                        o[0]  = d;    o[1]  = t2;   o[2]  = -t1;
                        o[40] = -t2;  o[41] = d;    o[42] = t0;
                        o[80] = t1;   o[81] = -t0;  o[82] = d;
                    }
                }
            }
            LGKM_BARRIER();             // scatter visible
            // coalesced nt copy-out: 8 rows = 3200 quads
            float* dstf = out + (size_t)(b0 + h * 8) * 1600;
            const f32x4* srcv = reinterpret_cast<const f32x4*>(smemf);
            #pragma unroll
            for (int k = 0; k < 13; ++k) {
                int p = tid + (k << 8);
                if (k < 12 || tid < 128) {
                    f32x4 val = srcv[p];
                    __builtin_nontemporal_store(
                        val, reinterpret_cast<f32x4*>(dstf + (size_t)p * 4));
                }
            }
        }
        cur ^= 1;
    }
}

extern "C" void kernel_launch(void* const* d_in, const int* in_sizes, int n_in,
                              void* d_out, int out_size, void* d_ws, size_t ws_size,
                              hipStream_t stream) {
    const float* x_in = (const float*)d_in[0];
    const float* weights = (const float*)d_in[1];
    float* out = (float*)d_out;
    unsigned short* w0t = (unsigned short*)d_ws;            // 320*128 bf16
    unsigned short* w1t = w0t + 320 * 128;                  // 320*64  bf16
    int B = in_sizes[0] / 320;                              // 100000

    prep_w<<<240, 256, 0, stream>>>(weights, w0t, w1t);
    qhnet_main<<<GRID, 256, 0, stream>>>(x_in, w0t, w1t, out, B / 16);
}